// Round 12
// baseline (211.307 us; speedup 1.0000x reference)
//
#include <hip/hip_runtime.h>
#include <cmath>

typedef _Float16 f16;
typedef _Float16 f16x8 __attribute__((ext_vector_type(8)));
typedef float    f32x16 __attribute__((ext_vector_type(16)));

#define NK 1024
#define ND 64
#define NTOT 131072

// d_ws layout: [0,4KB) u32 counts[1024]; [4KB,8KB) f32 g[1024] = -0.5*||e_k||^2;
//              [8KB, 8KB+256KB) f16x8 fragbuf[16384]  (split E fragments, if ws fits)

__global__ __launch_bounds__(1024) void vq_prep(const float* __restrict__ emb,
                                                unsigned int* __restrict__ counts,
                                                float* __restrict__ g) {
    int k = threadIdx.x;
    counts[k] = 0u;
    const float4* row = reinterpret_cast<const float4*>(emb + (size_t)k * ND);
    float s = 0.0f;
#pragma unroll
    for (int i = 0; i < ND/4; ++i) {
        float4 v = row[i];
        s += v.x*v.x + v.y*v.y + v.z*v.z + v.w*v.w;
    }
    g[k] = -0.5f * s;
}

// Precompute split E-fragments in MFMA frag order (bit-identical to the inline
// split of the round-8 kernel). frag t: cc=t>>11, f=t&2047, tt=f>>9,
// u=(f>>6)&7, ln=f&63; u4=u&3, islo=u>>2; code c=((cc*4+tt)*32)+(ln&31);
// dims d0..d0+7, d0=u4*16+(ln>>5)*8.
__global__ __launch_bounds__(256) void vq_prep_frags(const float* __restrict__ emb,
                                                     f16x8* __restrict__ frag) {
    int t  = blockIdx.x * 256 + threadIdx.x;   // 0..16383
    int f  = t & 2047;
    int cc = t >> 11;
    int tt = f >> 9;
    int u  = (f >> 6) & 7;
    int ln = f & 63;
    int u4 = u & 3, islo = u >> 2;
    int c  = (((cc << 2) + tt) << 5) + (ln & 31);
    int d0 = u4*16 + ((ln >> 5) << 3);
    const float4* src = reinterpret_cast<const float4*>(emb + ((size_t)c << 6) + d0);
    float4 va = src[0], vb = src[1];
    f16x8 o;
    if (islo) {
        o[0] = (f16)((va.x - (float)(f16)va.x) * 2048.0f);
        o[1] = (f16)((va.y - (float)(f16)va.y) * 2048.0f);
        o[2] = (f16)((va.z - (float)(f16)va.z) * 2048.0f);
        o[3] = (f16)((va.w - (float)(f16)va.w) * 2048.0f);
        o[4] = (f16)((vb.x - (float)(f16)vb.x) * 2048.0f);
        o[5] = (f16)((vb.y - (float)(f16)vb.y) * 2048.0f);
        o[6] = (f16)((vb.z - (float)(f16)vb.z) * 2048.0f);
        o[7] = (f16)((vb.w - (float)(f16)vb.w) * 2048.0f);
    } else {
        o[0] = (f16)va.x; o[1] = (f16)va.y; o[2] = (f16)va.z; o[3] = (f16)va.w;
        o[4] = (f16)vb.x; o[5] = (f16)vb.y; o[6] = (f16)vb.z; o[7] = (f16)vb.w;
    }
    frag[t] = o;
}

// fp16 double-split MFMA distances — numerics bit-identical to round 8:
// dot = A0 + A1*2^-11 + A2*2^-22, m = dot + g in the epilogue.
// PRE frags + Ef double-buffer + issue-early/write-late (T14), one barrier
// per chunk. Staging is in TYPED registers (f16x8 / float4, static indices,
// no address-taking) — round 11's reinterpret_cast<&local> punning demoted
// the staging array to scratch (307 MB spill writes).
template<bool PRE>
__global__ __launch_bounds__(512, 2) void vq_main(const float* __restrict__ in,
                                                  const float* __restrict__ emb,
                                                  const float* __restrict__ g,
                                                  const f16x8* __restrict__ frag,
                                                  unsigned int* __restrict__ counts,
                                                  float* __restrict__ out_idx,
                                                  float* __restrict__ out_q) {
    __shared__ f16x8 Ef[2][2048];   // 64KB
    __shared__ float gs[2][128];

    const int tid  = threadIdx.x;
    const int lane = tid & 63;
    const int wv   = tid >> 6;
    const int col  = lane & 31;
    const int hi   = lane >> 5;

    const int task = blockIdx.x * 8 + wv;   // 4096 tasks, 32 queries each
    const int q0   = task << 5;
    const int b    = q0 >> 12;
    const int hw0  = q0 & 4095;
    const int q    = q0 + col;

    // ---- query B-frags: xh + xl'*2^-11 (xl' prescaled 2048) ----
    const float* xb = in + ((size_t)b << 18) + hw0 + col;
    f16x8 xh[4], xl[4];
#pragma unroll
    for (int s = 0; s < 4; ++s) {
#pragma unroll
        for (int j = 0; j < 8; ++j) {
            float xv = xb[(size_t)(s*16 + hi*8 + j) << 12];
            f16 h = (f16)xv;
            xh[s][j] = h;
            xl[s][j] = (f16)((xv - (float)h) * 2048.0f);
        }
    }

    float bestm = -3.4e38f;
    int   bestk = 0;
    const float c1 = 4.8828125e-4f;           // 2^-11
    const float c2 = 2.384185791015625e-7f;   // 2^-22

    f16x8  ldf[4];               // PRE staging (typed, static-indexed)
    float4 lda[4], ldb[4];       // fallback staging
    float  gv0 = 0.0f;

    auto LOADS = [&](int cc) {
        if constexpr (PRE) {
            const f16x8* fp = frag + cc*2048;
#pragma unroll
            for (int i = 0; i < 4; ++i) ldf[i] = fp[i*512 + tid];
        } else {
#pragma unroll
            for (int i = 0; i < 4; ++i) {
                int f  = i*512 + tid;
                int tt = f >> 9;
                int u4 = (f >> 6) & 3;
                int ln = f & 63;
                int c  = (((cc << 2) + tt) << 5) + (ln & 31);
                int d0 = u4*16 + ((ln >> 5) << 3);
                const float4* src = reinterpret_cast<const float4*>(emb + ((size_t)c << 6) + d0);
                lda[i] = src[0];
                ldb[i] = src[1];
            }
        }
        if (tid < 128) gv0 = g[cc*128 + tid];
    };

    auto WRITES = [&](int buf) {
#pragma unroll
        for (int i = 0; i < 4; ++i) {
            int f = i*512 + tid;
            if constexpr (PRE) {
                Ef[buf][f] = ldf[i];
            } else {
                int islo = (f >> 8) & 1;  // bit2 of u
                f16x8 o;
                if (islo) {
                    o[0] = (f16)((lda[i].x - (float)(f16)lda[i].x) * 2048.0f);
                    o[1] = (f16)((lda[i].y - (float)(f16)lda[i].y) * 2048.0f);
                    o[2] = (f16)((lda[i].z - (float)(f16)lda[i].z) * 2048.0f);
                    o[3] = (f16)((lda[i].w - (float)(f16)lda[i].w) * 2048.0f);
                    o[4] = (f16)((ldb[i].x - (float)(f16)ldb[i].x) * 2048.0f);
                    o[5] = (f16)((ldb[i].y - (float)(f16)ldb[i].y) * 2048.0f);
                    o[6] = (f16)((ldb[i].z - (float)(f16)ldb[i].z) * 2048.0f);
                    o[7] = (f16)((ldb[i].w - (float)(f16)ldb[i].w) * 2048.0f);
                } else {
                    o[0] = (f16)lda[i].x; o[1] = (f16)lda[i].y;
                    o[2] = (f16)lda[i].z; o[3] = (f16)lda[i].w;
                    o[4] = (f16)ldb[i].x; o[5] = (f16)ldb[i].y;
                    o[6] = (f16)ldb[i].z; o[7] = (f16)ldb[i].w;
                }
                Ef[buf][f] = o;
            }
        }
        if (tid < 128) gs[buf][tid] = gv0;
    };

    LOADS(0);
    WRITES(0);
    __syncthreads();

#pragma unroll 1
    for (int cc = 0; cc < 8; ++cc) {
        const int cur = cc & 1;
        if (cc < 7) LOADS(cc + 1);

#pragma unroll
        for (int tt = 0; tt < 4; ++tt) {
            const f16x8* fb = &Ef[cur][tt*512 + lane];
            f32x16 a0 = {}, a1 = {}, a2 = {};
#pragma unroll
            for (int s = 0; s < 4; ++s) {
                f16x8 eh = fb[s*64];
                a0 = __builtin_amdgcn_mfma_f32_32x32x16_f16(eh, xh[s], a0, 0, 0, 0);
                a1 = __builtin_amdgcn_mfma_f32_32x32x16_f16(eh, xl[s], a1, 0, 0, 0);
                f16x8 el = fb[(4+s)*64];
                a1 = __builtin_amdgcn_mfma_f32_32x32x16_f16(el, xh[s], a1, 0, 0, 0);
                a2 = __builtin_amdgcn_mfma_f32_32x32x16_f16(el, xl[s], a2, 0, 0, 0);
            }
            // ---- m = dot + g[code]; maximize (== argmin dist) ----
            const int kbase = (((cc << 2) + tt) << 5);
            const float* gp = &gs[cur][tt*32 + (hi << 2)];
            float4 g0 = *reinterpret_cast<const float4*>(gp);
            float4 g1 = *reinterpret_cast<const float4*>(gp + 8);
            float4 g2 = *reinterpret_cast<const float4*>(gp + 16);
            float4 g3 = *reinterpret_cast<const float4*>(gp + 24);
#pragma unroll
            for (int r = 0; r < 16; ++r) {
                float m = fmaf(a2[r], c2, fmaf(a1[r], c1, a0[r]));
                float gg;
                switch (r >> 2) {
                    case 0: gg = (r&3)==0?g0.x:(r&3)==1?g0.y:(r&3)==2?g0.z:g0.w; break;
                    case 1: gg = (r&3)==0?g1.x:(r&3)==1?g1.y:(r&3)==2?g1.z:g1.w; break;
                    case 2: gg = (r&3)==0?g2.x:(r&3)==1?g2.y:(r&3)==2?g2.z:g2.w; break;
                    default:gg = (r&3)==0?g3.x:(r&3)==1?g3.y:(r&3)==2?g3.z:g3.w; break;
                }
                m += gg;
                // code rows ascend with r within this lane -> strict > = first-min
                int code = kbase + (r & 3) + ((r >> 2) << 3) + (hi << 2);
                if (m > bestm) { bestm = m; bestk = code; }
            }
        }

        if (cc < 7) WRITES(cur ^ 1);
        __syncthreads();
    }

    // ---- merge half-wave candidates (lower code wins ties) ----
    {
        float ob = __shfl_xor(bestm, 32, 64);
        int   oi = __shfl_xor(bestk, 32, 64);
        if (ob > bestm || (ob == bestm && oi < bestk)) { bestm = ob; bestk = oi; }
    }

    // ---- indices (as float) + histogram ----
    if (hi == 0) {
        out_idx[q] = (float)bestk;
        atomicAdd(&counts[bestk], 1u);
    }

    // ---- quantized (B,C,H,W): gather emb row (L2-hot), coalesced stores ----
    const float* er = emb + ((size_t)bestk << 6);
    float* ob_ = out_q + ((size_t)b << 18) + hw0 + col;
#pragma unroll
    for (int c4 = 0; c4 < 32; ++c4) {
        int c = hi*32 + c4;
        ob_[(size_t)c << 12] = er[c];
    }
}

__global__ __launch_bounds__(1024) void vq_perp(const unsigned int* __restrict__ counts,
                                                float* __restrict__ out_p) {
    __shared__ float red[16];
    int tid = threadIdx.x;  // 1024
    float p = (float)counts[tid] * (1.0f / (float)NTOT);
    float t = p * logf(p + 1e-10f);
#pragma unroll
    for (int m = 1; m < 64; m <<= 1) t += __shfl_xor(t, m, 64);
    if ((tid & 63) == 0) red[tid >> 6] = t;
    __syncthreads();
    if (tid < 16) {
        float s = red[tid];
#pragma unroll
        for (int m = 1; m < 16; m <<= 1) s += __shfl_xor(s, m, 64);
        if (tid == 0) out_p[0] = expf(-s);
    }
}

extern "C" void kernel_launch(void* const* d_in, const int* in_sizes, int n_in,
                              void* d_out, int out_size, void* d_ws, size_t ws_size,
                              hipStream_t stream) {
    const float* in  = (const float*)d_in[0];   // (32, 64, 64, 64)
    const float* emb = (const float*)d_in[1];   // (1024, 64)
    float* out = (float*)d_out;

    unsigned int* counts = (unsigned int*)d_ws;
    float* g = (float*)d_ws + NK;
    f16x8* frag = (f16x8*)((char*)d_ws + 8192);

    float* out_idx = out;                       // 131072
    float* out_q   = out + NTOT;                // 8388608
    float* out_p   = out + NTOT + (size_t)NTOT * ND;  // 1

    const bool pre = ws_size >= (size_t)(8192 + 16384 * 16);

    vq_prep<<<1, 1024, 0, stream>>>(emb, counts, g);
    if (pre) {
        vq_prep_frags<<<64, 256, 0, stream>>>(emb, frag);
        vq_main<true><<<512, 512, 0, stream>>>(in, emb, g, frag, counts, out_idx, out_q);
    } else {
        vq_main<false><<<512, 512, 0, stream>>>(in, emb, g, frag, counts, out_idx, out_q);
    }
    vq_perp<<<1, 1024, 0, stream>>>(counts, out_p);
}

// Round 13
// 114.528 us; speedup vs baseline: 1.8450x; 1.8450x over previous
//
#include <hip/hip_runtime.h>
#include <cmath>

typedef _Float16 f16;
typedef _Float16 f16x8 __attribute__((ext_vector_type(8)));
typedef float    f32x16 __attribute__((ext_vector_type(16)));

#define NK 1024
#define ND 64
#define NTOT 131072

// d_ws layout: [0,4KB) u32 counts[1024]; [4KB,8KB) f32 g[1024] = -0.5*||e_k||^2;
//              [8KB, 8KB+256KB) f16x8 fragbuf[16384]  (split E fragments, if ws fits)

__global__ __launch_bounds__(1024) void vq_prep(const float* __restrict__ emb,
                                                unsigned int* __restrict__ counts,
                                                float* __restrict__ g) {
    int k = threadIdx.x;
    counts[k] = 0u;
    const float4* row = reinterpret_cast<const float4*>(emb + (size_t)k * ND);
    float s = 0.0f;
#pragma unroll
    for (int i = 0; i < ND/4; ++i) {
        float4 v = row[i];
        s += v.x*v.x + v.y*v.y + v.z*v.z + v.w*v.w;
    }
    g[k] = -0.5f * s;
}

// Precompute split E-fragments in MFMA frag order (bit-identical to the
// round-8 inline split). frag t: cc=t>>11, f=t&2047, tt=f>>9, u=(f>>6)&7,
// ln=f&63; u4=u&3, islo=u>>2; code c=((cc*4+tt)*32)+(ln&31); d0=u4*16+(ln>>5)*8.
__global__ __launch_bounds__(256) void vq_prep_frags(const float* __restrict__ emb,
                                                     f16x8* __restrict__ frag) {
    int t  = blockIdx.x * 256 + threadIdx.x;   // 0..16383
    int f  = t & 2047;
    int cc = t >> 11;
    int tt = f >> 9;
    int u  = (f >> 6) & 7;
    int ln = f & 63;
    int u4 = u & 3, islo = u >> 2;
    int c  = (((cc << 2) + tt) << 5) + (ln & 31);
    int d0 = u4*16 + ((ln >> 5) << 3);
    const float4* src = reinterpret_cast<const float4*>(emb + ((size_t)c << 6) + d0);
    float4 va = src[0], vb = src[1];
    f16x8 o;
    if (islo) {
        o[0] = (f16)((va.x - (float)(f16)va.x) * 2048.0f);
        o[1] = (f16)((va.y - (float)(f16)va.y) * 2048.0f);
        o[2] = (f16)((va.z - (float)(f16)va.z) * 2048.0f);
        o[3] = (f16)((va.w - (float)(f16)va.w) * 2048.0f);
        o[4] = (f16)((vb.x - (float)(f16)vb.x) * 2048.0f);
        o[5] = (f16)((vb.y - (float)(f16)vb.y) * 2048.0f);
        o[6] = (f16)((vb.z - (float)(f16)vb.z) * 2048.0f);
        o[7] = (f16)((vb.w - (float)(f16)vb.w) * 2048.0f);
    } else {
        o[0] = (f16)va.x; o[1] = (f16)va.y; o[2] = (f16)va.z; o[3] = (f16)va.w;
        o[4] = (f16)vb.x; o[5] = (f16)vb.y; o[6] = (f16)vb.z; o[7] = (f16)vb.w;
    }
    frag[t] = o;
}

// fp16 double-split MFMA distances — numerics bit-identical to round 8:
// dot = A0 + A1*2^-11 + A2*2^-22, m = dot + g in the epilogue.
// Staging via global_load_lds (async HW DMA, zero registers): register-staged
// prefetch (rounds 10-12) spilled ~146B/thread/chunk because staged values
// must live across the 48-MFMA tt-loop -> 307MB scratch writes + L2 thrash.
// g is loaded to LDS ONCE per block (4KB), no per-chunk staging.
template<bool PRE>
__global__ __launch_bounds__(512, 2) void vq_main(const float* __restrict__ in,
                                                  const float* __restrict__ emb,
                                                  const float* __restrict__ g,
                                                  const f16x8* __restrict__ frag,
                                                  unsigned int* __restrict__ counts,
                                                  float* __restrict__ out_idx,
                                                  float* __restrict__ out_q) {
    __shared__ f16x8 Ef[2][2048];   // 64KB
    __shared__ float gs_all[1024];  // 4KB, loaded once

    const int tid  = threadIdx.x;
    const int lane = tid & 63;
    const int wv   = tid >> 6;
    const int col  = lane & 31;
    const int hi   = lane >> 5;

    const int task = blockIdx.x * 8 + wv;   // 4096 tasks, 32 queries each
    const int q0   = task << 5;
    const int b    = q0 >> 12;
    const int hw0  = q0 & 4095;
    const int q    = q0 + col;

    // ---- query B-frags: xh + xl'*2^-11 (xl' prescaled 2048) ----
    const float* xb = in + ((size_t)b << 18) + hw0 + col;
    f16x8 xh[4], xl[4];
#pragma unroll
    for (int s = 0; s < 4; ++s) {
#pragma unroll
        for (int j = 0; j < 8; ++j) {
            float xv = xb[(size_t)(s*16 + hi*8 + j) << 12];
            f16 h = (f16)xv;
            xh[s][j] = h;
            xl[s][j] = (f16)((xv - (float)h) * 2048.0f);
        }
    }

    float bestm = -3.4e38f;
    int   bestk = 0;
    const float c1 = 4.8828125e-4f;           // 2^-11
    const float c2 = 2.384185791015625e-7f;   // 2^-22

    // ---- async stage chunk cc into Ef[buf]: HW DMA, no VGPR round-trip ----
    auto STAGE = [&](int cc, int buf) {
        if constexpr (PRE) {
            const f16x8* fp = frag + cc*2048 + (wv << 6) + lane;  // per-lane src
#pragma unroll
            for (int i = 0; i < 4; ++i) {
                __builtin_amdgcn_global_load_lds(
                    (const __attribute__((address_space(1))) void*)(fp + i*512),
                    (__attribute__((address_space(3))) void*)&Ef[buf][i*512 + (wv << 6)],
                    16, 0, 0);
            }
        } else {
            // fallback: direct load+split+write (no cross-phase liveness)
#pragma unroll
            for (int i = 0; i < 4; ++i) {
                int f  = i*512 + tid;
                int tt = f >> 9;
                int u4 = (f >> 6) & 3;
                int ln = f & 63;
                int c  = (((cc << 2) + tt) << 5) + (ln & 31);
                int d0 = u4*16 + ((ln >> 5) << 3);
                const float4* src = reinterpret_cast<const float4*>(emb + ((size_t)c << 6) + d0);
                float4 va = src[0], vb = src[1];
                int islo = (f >> 8) & 1;
                f16x8 o;
                if (islo) {
                    o[0] = (f16)((va.x - (float)(f16)va.x) * 2048.0f);
                    o[1] = (f16)((va.y - (float)(f16)va.y) * 2048.0f);
                    o[2] = (f16)((va.z - (float)(f16)va.z) * 2048.0f);
                    o[3] = (f16)((va.w - (float)(f16)va.w) * 2048.0f);
                    o[4] = (f16)((vb.x - (float)(f16)vb.x) * 2048.0f);
                    o[5] = (f16)((vb.y - (float)(f16)vb.y) * 2048.0f);
                    o[6] = (f16)((vb.z - (float)(f16)vb.z) * 2048.0f);
                    o[7] = (f16)((vb.w - (float)(f16)vb.w) * 2048.0f);
                } else {
                    o[0] = (f16)va.x; o[1] = (f16)va.y; o[2] = (f16)va.z; o[3] = (f16)va.w;
                    o[4] = (f16)vb.x; o[5] = (f16)vb.y; o[6] = (f16)vb.z; o[7] = (f16)vb.w;
                }
                Ef[buf][f] = o;
            }
        }
    };

    // ---- g to LDS once ----
    gs_all[tid]       = g[tid];
    gs_all[tid + 512] = g[tid + 512];
    STAGE(0, 0);
    __syncthreads();   // drains vmcnt -> Ef[0] + gs_all ready

#pragma unroll 1
    for (int cc = 0; cc < 8; ++cc) {
        const int cur = cc & 1;
        if (cc < 7) STAGE(cc + 1, cur ^ 1);   // async under this chunk's MFMAs

#pragma unroll
        for (int tt = 0; tt < 4; ++tt) {
            const f16x8* fb = &Ef[cur][tt*512 + lane];
            f32x16 a0 = {}, a1 = {}, a2 = {};
#pragma unroll
            for (int s = 0; s < 4; ++s) {
                f16x8 eh = fb[s*64];
                a0 = __builtin_amdgcn_mfma_f32_32x32x16_f16(eh, xh[s], a0, 0, 0, 0);
                a1 = __builtin_amdgcn_mfma_f32_32x32x16_f16(eh, xl[s], a1, 0, 0, 0);
                f16x8 el = fb[(4+s)*64];
                a1 = __builtin_amdgcn_mfma_f32_32x32x16_f16(el, xh[s], a1, 0, 0, 0);
                a2 = __builtin_amdgcn_mfma_f32_32x32x16_f16(el, xl[s], a2, 0, 0, 0);
            }
            // ---- m = dot + g[code]; maximize (== argmin dist) ----
            const int kbase = (((cc << 2) + tt) << 5);
            const float* gp = &gs_all[kbase + (hi << 2)];
            float4 g0 = *reinterpret_cast<const float4*>(gp);
            float4 g1 = *reinterpret_cast<const float4*>(gp + 8);
            float4 g2 = *reinterpret_cast<const float4*>(gp + 16);
            float4 g3 = *reinterpret_cast<const float4*>(gp + 24);
#pragma unroll
            for (int r = 0; r < 16; ++r) {
                float m = fmaf(a2[r], c2, fmaf(a1[r], c1, a0[r]));
                float gg;
                switch (r >> 2) {
                    case 0: gg = (r&3)==0?g0.x:(r&3)==1?g0.y:(r&3)==2?g0.z:g0.w; break;
                    case 1: gg = (r&3)==0?g1.x:(r&3)==1?g1.y:(r&3)==2?g1.z:g1.w; break;
                    case 2: gg = (r&3)==0?g2.x:(r&3)==1?g2.y:(r&3)==2?g2.z:g2.w; break;
                    default:gg = (r&3)==0?g3.x:(r&3)==1?g3.y:(r&3)==2?g3.z:g3.w; break;
                }
                m += gg;
                // code rows ascend with r within this lane -> strict > = first-min
                int code = kbase + (r & 3) + ((r >> 2) << 3) + (hi << 2);
                if (m > bestm) { bestm = m; bestk = code; }
            }
        }

        __syncthreads();   // drains vmcnt: next buffer complete; Ef[cur] free
    }

    // ---- merge half-wave candidates (lower code wins ties) ----
    {
        float ob = __shfl_xor(bestm, 32, 64);
        int   oi = __shfl_xor(bestk, 32, 64);
        if (ob > bestm || (ob == bestm && oi < bestk)) { bestm = ob; bestk = oi; }
    }

    // ---- indices (as float) + histogram ----
    if (hi == 0) {
        out_idx[q] = (float)bestk;
        atomicAdd(&counts[bestk], 1u);
    }

    // ---- quantized (B,C,H,W): gather emb row (L2-hot), coalesced stores ----
    const float* er = emb + ((size_t)bestk << 6);
    float* ob_ = out_q + ((size_t)b << 18) + hw0 + col;
#pragma unroll
    for (int c4 = 0; c4 < 32; ++c4) {
        int c = hi*32 + c4;
        ob_[(size_t)c << 12] = er[c];
    }
}

__global__ __launch_bounds__(1024) void vq_perp(const unsigned int* __restrict__ counts,
                                                float* __restrict__ out_p) {
    __shared__ float red[16];
    int tid = threadIdx.x;  // 1024
    float p = (float)counts[tid] * (1.0f / (float)NTOT);
    float t = p * logf(p + 1e-10f);
#pragma unroll
    for (int m = 1; m < 64; m <<= 1) t += __shfl_xor(t, m, 64);
    if ((tid & 63) == 0) red[tid >> 6] = t;
    __syncthreads();
    if (tid < 16) {
        float s = red[tid];
#pragma unroll
        for (int m = 1; m < 16; m <<= 1) s += __shfl_xor(s, m, 64);
        if (tid == 0) out_p[0] = expf(-s);
    }
}

extern "C" void kernel_launch(void* const* d_in, const int* in_sizes, int n_in,
                              void* d_out, int out_size, void* d_ws, size_t ws_size,
                              hipStream_t stream) {
    const float* in  = (const float*)d_in[0];   // (32, 64, 64, 64)
    const float* emb = (const float*)d_in[1];   // (1024, 64)
    float* out = (float*)d_out;

    unsigned int* counts = (unsigned int*)d_ws;
    float* g = (float*)d_ws + NK;
    f16x8* frag = (f16x8*)((char*)d_ws + 8192);

    float* out_idx = out;                       // 131072
    float* out_q   = out + NTOT;                // 8388608
    float* out_p   = out + NTOT + (size_t)NTOT * ND;  // 1

    const bool pre = ws_size >= (size_t)(8192 + 16384 * 16);

    vq_prep<<<1, 1024, 0, stream>>>(emb, counts, g);
    if (pre) {
        vq_prep_frags<<<64, 256, 0, stream>>>(emb, frag);
        vq_main<true><<<512, 512, 0, stream>>>(in, emb, g, frag, counts, out_idx, out_q);
    } else {
        vq_main<false><<<512, 512, 0, stream>>>(in, emb, g, frag, counts, out_idx, out_q);
    }
    vq_perp<<<1, 1024, 0, stream>>>(counts, out_p);
}

// Round 14
// 111.392 us; speedup vs baseline: 1.8970x; 1.0282x over previous
//
#include <hip/hip_runtime.h>
#include <cmath>

typedef _Float16 f16;
typedef _Float16 f16x8 __attribute__((ext_vector_type(8)));
typedef float    f32x16 __attribute__((ext_vector_type(16)));

#define NK 1024
#define ND 64
#define NTOT 131072

// d_ws layout: [0,4KB) u32 counts[1024]; [4KB,8KB) f32 g[1024] = -0.5*||e_k||^2;
//              [8KB, 8KB+256KB) f16x8 fragbuf[16384]  (split E fragments, if ws fits)

// Fused prep: split E-fragments in MFMA frag order (bit-identical to the
// round-8 inline split) + counts zero + g. frag t: cc=t>>11, f=t&2047,
// tt=f>>9, u=(f>>6)&7, ln=f&63; u4=u&3, islo=u>>2; code c=((cc*4+tt)*32)+(ln&31);
// d0=u4*16+(ln>>5)*8.
__global__ __launch_bounds__(256) void vq_prep_all(const float* __restrict__ emb,
                                                   f16x8* __restrict__ frag,
                                                   unsigned int* __restrict__ counts,
                                                   float* __restrict__ g) {
    int t  = blockIdx.x * 256 + threadIdx.x;   // 0..16383
    int f  = t & 2047;
    int cc = t >> 11;
    int tt = f >> 9;
    int u  = (f >> 6) & 7;
    int ln = f & 63;
    int u4 = u & 3, islo = u >> 2;
    int c  = (((cc << 2) + tt) << 5) + (ln & 31);
    int d0 = u4*16 + ((ln >> 5) << 3);
    const float4* src = reinterpret_cast<const float4*>(emb + ((size_t)c << 6) + d0);
    float4 va = src[0], vb = src[1];
    f16x8 o;
    if (islo) {
        o[0] = (f16)((va.x - (float)(f16)va.x) * 2048.0f);
        o[1] = (f16)((va.y - (float)(f16)va.y) * 2048.0f);
        o[2] = (f16)((va.z - (float)(f16)va.z) * 2048.0f);
        o[3] = (f16)((va.w - (float)(f16)va.w) * 2048.0f);
        o[4] = (f16)((vb.x - (float)(f16)vb.x) * 2048.0f);
        o[5] = (f16)((vb.y - (float)(f16)vb.y) * 2048.0f);
        o[6] = (f16)((vb.z - (float)(f16)vb.z) * 2048.0f);
        o[7] = (f16)((vb.w - (float)(f16)vb.w) * 2048.0f);
    } else {
        o[0] = (f16)va.x; o[1] = (f16)va.y; o[2] = (f16)va.z; o[3] = (f16)va.w;
        o[4] = (f16)vb.x; o[5] = (f16)vb.y; o[6] = (f16)vb.z; o[7] = (f16)vb.w;
    }
    frag[t] = o;

    // fused vq_prep: one thread per code for counts + g
    if (t < NK) {
        counts[t] = 0u;
        const float4* row = reinterpret_cast<const float4*>(emb + (size_t)t * ND);
        float s = 0.0f;
#pragma unroll
        for (int i = 0; i < ND/4; ++i) {
            float4 v = row[i];
            s += v.x*v.x + v.y*v.y + v.z*v.z + v.w*v.w;
        }
        g[t] = -0.5f * s;
    }
}

// fp16 double-split MFMA distances — numerics bit-identical to round 8:
// dot = A0 + A1*2^-11 + A2*2^-22, m = dot + g in the epilogue.
// Staging via global_load_lds (async HW DMA, zero registers). g in LDS once.
// T5: setprio(1) around the MFMA cluster (phase diversity across the 2
// independent blocks/CU).
template<bool PRE>
__global__ __launch_bounds__(512, 2) void vq_main(const float* __restrict__ in,
                                                  const float* __restrict__ emb,
                                                  const float* __restrict__ g,
                                                  const f16x8* __restrict__ frag,
                                                  unsigned int* __restrict__ counts,
                                                  float* __restrict__ out_idx,
                                                  float* __restrict__ out_q) {
    __shared__ f16x8 Ef[2][2048];   // 64KB
    __shared__ float gs_all[1024];  // 4KB, loaded once

    const int tid  = threadIdx.x;
    const int lane = tid & 63;
    const int wv   = tid >> 6;
    const int col  = lane & 31;
    const int hi   = lane >> 5;

    const int task = blockIdx.x * 8 + wv;   // 4096 tasks, 32 queries each
    const int q0   = task << 5;
    const int b    = q0 >> 12;
    const int hw0  = q0 & 4095;
    const int q    = q0 + col;

    // ---- query B-frags: xh + xl'*2^-11 (xl' prescaled 2048) ----
    const float* xb = in + ((size_t)b << 18) + hw0 + col;
    f16x8 xh[4], xl[4];
#pragma unroll
    for (int s = 0; s < 4; ++s) {
#pragma unroll
        for (int j = 0; j < 8; ++j) {
            float xv = xb[(size_t)(s*16 + hi*8 + j) << 12];
            f16 h = (f16)xv;
            xh[s][j] = h;
            xl[s][j] = (f16)((xv - (float)h) * 2048.0f);
        }
    }

    float bestm = -3.4e38f;
    int   bestk = 0;
    const float c1 = 4.8828125e-4f;           // 2^-11
    const float c2 = 2.384185791015625e-7f;   // 2^-22

    // ---- async stage chunk cc into Ef[buf]: HW DMA, no VGPR round-trip ----
    auto STAGE = [&](int cc, int buf) {
        if constexpr (PRE) {
            const f16x8* fp = frag + cc*2048 + (wv << 6) + lane;  // per-lane src
#pragma unroll
            for (int i = 0; i < 4; ++i) {
                __builtin_amdgcn_global_load_lds(
                    (const __attribute__((address_space(1))) void*)(fp + i*512),
                    (__attribute__((address_space(3))) void*)&Ef[buf][i*512 + (wv << 6)],
                    16, 0, 0);
            }
        } else {
            // fallback: direct load+split+write (no cross-phase liveness)
#pragma unroll
            for (int i = 0; i < 4; ++i) {
                int f  = i*512 + tid;
                int tt = f >> 9;
                int u4 = (f >> 6) & 3;
                int ln = f & 63;
                int c  = (((cc << 2) + tt) << 5) + (ln & 31);
                int d0 = u4*16 + ((ln >> 5) << 3);
                const float4* src = reinterpret_cast<const float4*>(emb + ((size_t)c << 6) + d0);
                float4 va = src[0], vb = src[1];
                int islo = (f >> 8) & 1;
                f16x8 o;
                if (islo) {
                    o[0] = (f16)((va.x - (float)(f16)va.x) * 2048.0f);
                    o[1] = (f16)((va.y - (float)(f16)va.y) * 2048.0f);
                    o[2] = (f16)((va.z - (float)(f16)va.z) * 2048.0f);
                    o[3] = (f16)((va.w - (float)(f16)va.w) * 2048.0f);
                    o[4] = (f16)((vb.x - (float)(f16)vb.x) * 2048.0f);
                    o[5] = (f16)((vb.y - (float)(f16)vb.y) * 2048.0f);
                    o[6] = (f16)((vb.z - (float)(f16)vb.z) * 2048.0f);
                    o[7] = (f16)((vb.w - (float)(f16)vb.w) * 2048.0f);
                } else {
                    o[0] = (f16)va.x; o[1] = (f16)va.y; o[2] = (f16)va.z; o[3] = (f16)va.w;
                    o[4] = (f16)vb.x; o[5] = (f16)vb.y; o[6] = (f16)vb.z; o[7] = (f16)vb.w;
                }
                Ef[buf][f] = o;
            }
        }
    };

    // ---- g to LDS once ----
    gs_all[tid]       = g[tid];
    gs_all[tid + 512] = g[tid + 512];
    STAGE(0, 0);
    __syncthreads();   // drains vmcnt -> Ef[0] + gs_all ready

#pragma unroll 1
    for (int cc = 0; cc < 8; ++cc) {
        const int cur = cc & 1;
        if (cc < 7) STAGE(cc + 1, cur ^ 1);   // async under this chunk's MFMAs

#pragma unroll
        for (int tt = 0; tt < 4; ++tt) {
            const f16x8* fb = &Ef[cur][tt*512 + lane];
            f32x16 a0 = {}, a1 = {}, a2 = {};
            __builtin_amdgcn_s_setprio(1);
#pragma unroll
            for (int s = 0; s < 4; ++s) {
                f16x8 eh = fb[s*64];
                a0 = __builtin_amdgcn_mfma_f32_32x32x16_f16(eh, xh[s], a0, 0, 0, 0);
                a1 = __builtin_amdgcn_mfma_f32_32x32x16_f16(eh, xl[s], a1, 0, 0, 0);
                f16x8 el = fb[(4+s)*64];
                a1 = __builtin_amdgcn_mfma_f32_32x32x16_f16(el, xh[s], a1, 0, 0, 0);
                a2 = __builtin_amdgcn_mfma_f32_32x32x16_f16(el, xl[s], a2, 0, 0, 0);
            }
            __builtin_amdgcn_s_setprio(0);
            // ---- m = dot + g[code]; maximize (== argmin dist) ----
            const int kbase = (((cc << 2) + tt) << 5);
            const float* gp = &gs_all[kbase + (hi << 2)];
            float4 g0 = *reinterpret_cast<const float4*>(gp);
            float4 g1 = *reinterpret_cast<const float4*>(gp + 8);
            float4 g2 = *reinterpret_cast<const float4*>(gp + 16);
            float4 g3 = *reinterpret_cast<const float4*>(gp + 24);
#pragma unroll
            for (int r = 0; r < 16; ++r) {
                float m = fmaf(a2[r], c2, fmaf(a1[r], c1, a0[r]));
                float gg;
                switch (r >> 2) {
                    case 0: gg = (r&3)==0?g0.x:(r&3)==1?g0.y:(r&3)==2?g0.z:g0.w; break;
                    case 1: gg = (r&3)==0?g1.x:(r&3)==1?g1.y:(r&3)==2?g1.z:g1.w; break;
                    case 2: gg = (r&3)==0?g2.x:(r&3)==1?g2.y:(r&3)==2?g2.z:g2.w; break;
                    default:gg = (r&3)==0?g3.x:(r&3)==1?g3.y:(r&3)==2?g3.z:g3.w; break;
                }
                m += gg;
                // code rows ascend with r within this lane -> strict > = first-min
                int code = kbase + (r & 3) + ((r >> 2) << 3) + (hi << 2);
                if (m > bestm) { bestm = m; bestk = code; }
            }
        }

        __syncthreads();   // drains vmcnt: next buffer complete; Ef[cur] free
    }

    // ---- merge half-wave candidates (lower code wins ties) ----
    {
        float ob = __shfl_xor(bestm, 32, 64);
        int   oi = __shfl_xor(bestk, 32, 64);
        if (ob > bestm || (ob == bestm && oi < bestk)) { bestm = ob; bestk = oi; }
    }

    // ---- indices (as float) + histogram ----
    if (hi == 0) {
        out_idx[q] = (float)bestk;
        atomicAdd(&counts[bestk], 1u);
    }

    // ---- quantized (B,C,H,W): gather emb row (L2-hot), coalesced stores ----
    const float* er = emb + ((size_t)bestk << 6);
    float* ob_ = out_q + ((size_t)b << 18) + hw0 + col;
#pragma unroll
    for (int c4 = 0; c4 < 32; ++c4) {
        int c = hi*32 + c4;
        ob_[(size_t)c << 12] = er[c];
    }
}

__global__ __launch_bounds__(1024) void vq_perp(const unsigned int* __restrict__ counts,
                                                float* __restrict__ out_p) {
    __shared__ float red[16];
    int tid = threadIdx.x;  // 1024
    float p = (float)counts[tid] * (1.0f / (float)NTOT);
    float t = p * logf(p + 1e-10f);
#pragma unroll
    for (int m = 1; m < 64; m <<= 1) t += __shfl_xor(t, m, 64);
    if ((tid & 63) == 0) red[tid >> 6] = t;
    __syncthreads();
    if (tid < 16) {
        float s = red[tid];
#pragma unroll
        for (int m = 1; m < 16; m <<= 1) s += __shfl_xor(s, m, 64);
        if (tid == 0) out_p[0] = expf(-s);
    }
}

extern "C" void kernel_launch(void* const* d_in, const int* in_sizes, int n_in,
                              void* d_out, int out_size, void* d_ws, size_t ws_size,
                              hipStream_t stream) {
    const float* in  = (const float*)d_in[0];   // (32, 64, 64, 64)
    const float* emb = (const float*)d_in[1];   // (1024, 64)
    float* out = (float*)d_out;

    unsigned int* counts = (unsigned int*)d_ws;
    float* g = (float*)d_ws + NK;
    f16x8* frag = (f16x8*)((char*)d_ws + 8192);

    float* out_idx = out;                       // 131072
    float* out_q   = out + NTOT;                // 8388608
    float* out_p   = out + NTOT + (size_t)NTOT * ND;  // 1

    const bool pre = ws_size >= (size_t)(8192 + 16384 * 16);

    if (pre) {
        vq_prep_all<<<64, 256, 0, stream>>>(emb, frag, counts, g);
        vq_main<true><<<512, 512, 0, stream>>>(in, emb, g, frag, counts, out_idx, out_q);
    } else {
        vq_prep_all<<<64, 256, 0, stream>>>(emb, frag, counts, g);  // frag unused later
        vq_main<false><<<512, 512, 0, stream>>>(in, emb, g, frag, counts, out_idx, out_q);
    }
    vq_perp<<<1, 1024, 0, stream>>>(counts, out_p);
}